// Round 2
// baseline (936.918 us; speedup 1.0000x reference)
//
#include <hip/hip_runtime.h>

#define NB   16384
#define LSEQ 50
#define D    100
#define KP   100
#define FF   2048
#define CH   128
#define NCH  (FF/CH)
#define ROWS 32
#define EPSV 1e-5f
#define SW   102   // LDS stride (u16) for Wv/Wo/W2 transposed tiles
#define SW1  132   // LDS stride (u16) for W1 transposed tile

typedef unsigned short u16;
typedef unsigned int   u32;

__device__ __forceinline__ float bflo(u32 u){ return __uint_as_float(u << 16); }
__device__ __forceinline__ float bfhi(u32 u){ return __uint_as_float(u & 0xffff0000u); }
__device__ __forceinline__ u16 f2bf(float f){
    u32 b = __float_as_uint(f);
    b += 0x7fffu + ((b >> 16) & 1u);   // round-to-nearest-even
    return (u16)(b >> 16);
}

// ---------------- Kernel 1: x = sum_l item_emb[item_seq[b,l]]  (fp32) --------
__global__ __launch_bounds__(256) void k_gather(const int* __restrict__ seq,
        const float* __restrict__ emb, float* __restrict__ xout)
{
    const int lane = threadIdx.x & 63;
    const int row  = (blockIdx.x << 2) + (threadIdx.x >> 6);
    int myidx = (lane < LSEQ) ? seq[row * LSEQ + lane] : 0;
    float ax = 0.f, ay = 0.f;
    const float2* e2 = (const float2*)emb;      // 50 float2 per row
    for (int l = 0; l < LSEQ; ++l) {
        int idx = __shfl(myidx, l, 64);
        if (lane < 50) {
            float2 w = e2[(size_t)idx * 50 + lane];
            ax += w.x; ay += w.y;
        }
    }
    if (lane < 50) {
        float2 v; v.x = ax; v.y = ay;
        ((float2*)xout)[(size_t)row * 50 + lane] = v;
    }
}

// ---------------- Kernel 2: fully fused transformer block + scoring ----------
__device__ __forceinline__ void stage_w_t(const float* __restrict__ src,
        u16* __restrict__ dst, int tid)
{
    // src: [100][100] fp32 row-major W[c][k] -> dst[k*SW + c] (bf16, transposed)
    for (int i = tid; i < D * D; i += 256) {
        int c = i / D, k = i % D;
        dst[k * SW + c] = f2bf(src[i]);
    }
}

template<bool ADD>
__device__ __forceinline__ void gemm_tile_100(const float* __restrict__ X,
        float* __restrict__ Y, const u16* __restrict__ Wt,
        const float* __restrict__ bias, int tid)
{
    if (tid >= 200) return;
    const int r0 = (tid / 25) * 4;
    const int c0 = (tid % 25) * 4;
    float acc[4][4] = {};
    for (int k = 0; k < D; ++k) {
        float xr[4];
        #pragma unroll
        for (int i = 0; i < 4; ++i) xr[i] = X[(r0 + i) * D + k];
        u32 wa = *(const u32*)&Wt[k * SW + c0];
        u32 wb = *(const u32*)&Wt[k * SW + c0 + 2];
        float wr[4] = { bflo(wa), bfhi(wa), bflo(wb), bfhi(wb) };
        #pragma unroll
        for (int i = 0; i < 4; ++i)
            #pragma unroll
            for (int j = 0; j < 4; ++j)
                acc[i][j] += xr[i] * wr[j];
    }
    #pragma unroll
    for (int i = 0; i < 4; ++i)
        #pragma unroll
        for (int j = 0; j < 4; ++j) {
            float v = acc[i][j] + bias[c0 + j];
            if (ADD) Y[(r0 + i) * D + c0 + j] += v;
            else     Y[(r0 + i) * D + c0 + j]  = v;
        }
}

__device__ __forceinline__ void layernorm_tile(const float* __restrict__ src,
        float* __restrict__ dst, const float* __restrict__ g,
        const float* __restrict__ b, int tid)
{
    const int r  = tid >> 3;   // 32 rows, 8 threads each
    const int s8 = tid & 7;
    float sum = 0.f, sq = 0.f;
    for (int k = s8; k < D; k += 8) {
        float v = src[r * D + k];
        sum += v; sq += v * v;
    }
    sum += __shfl_xor(sum, 1, 64); sq += __shfl_xor(sq, 1, 64);
    sum += __shfl_xor(sum, 2, 64); sq += __shfl_xor(sq, 2, 64);
    sum += __shfl_xor(sum, 4, 64); sq += __shfl_xor(sq, 4, 64);
    float m   = sum * 0.01f;
    float var = sq * 0.01f - m * m;
    float rs  = rsqrtf(var + EPSV);
    for (int k = s8; k < D; k += 8) {
        float v = src[r * D + k];
        dst[r * D + k] = (v - m) * rs * g[k] + b[k];
    }
}

__global__ __launch_bounds__(256) void k_fused(
    const float* __restrict__ xin,
    const int*  __restrict__ ipred,
    const float* __restrict__ rec_emb, const float* __restrict__ rec_b,
    const float* __restrict__ in_proj_w, const float* __restrict__ in_proj_b,
    const float* __restrict__ out_proj_w, const float* __restrict__ out_proj_b,
    const float* __restrict__ ln1g, const float* __restrict__ ln1b,
    const float* __restrict__ ln2g, const float* __restrict__ ln2b,
    const float* __restrict__ w1, const float* __restrict__ b1,
    const float* __restrict__ w2, const float* __restrict__ b2,
    float* __restrict__ out)
{
    __shared__ float A0[ROWS * D];     // x -> x+attn -> (h+f2) -> s
    __shared__ float A1[ROWS * D];     // v -> h
    __shared__ u32   WSu[6600];        // staged bf16 weights (13200 u16)
    __shared__ u32   HBu[ROWS * 66];   // H chunk, bf16 [32][132]
    u16* WSs = (u16*)WSu;

    const int tid  = threadIdx.x;
    const int row0 = blockIdx.x * ROWS;

    // load x tile + stage Wv (rows 200..299 of in_proj_w) transposed
    for (int i = tid; i < ROWS * D; i += 256)
        A0[i] = xin[(size_t)row0 * D + i];
    stage_w_t(in_proj_w + 2 * D * D, WSs, tid);
    __syncthreads();

    // v = x @ Wv^T + bv  -> A1
    gemm_tile_100<false>(A0, A1, WSs, in_proj_b + 2 * D, tid);
    __syncthreads();

    stage_w_t(out_proj_w, WSs, tid);
    __syncthreads();

    // attn = v @ Wo^T + bo ; A0 += attn
    gemm_tile_100<true>(A1, A0, WSs, out_proj_b, tid);
    __syncthreads();

    // h = LN1(x + attn) -> A1
    layernorm_tile(A0, A1, ln1g, ln1b, tid);
    __syncthreads();

    // ---------------- FFN, hidden chunked by 128 ----------------
    const int fr0 = (tid / 25) * 4;    // GEMM2 tile (tid<200)
    const int fc0 = (tid % 25) * 4;
    float facc[4][4] = {};

    for (int ch = 0; ch < NCH; ++ch) {
        // stage W1 chunk transposed: WSs[k*SW1 + j] = w1[ch*128 + j][k]
        {
            const float* s = w1 + (size_t)ch * CH * D;
            for (int i = tid; i < CH * D; i += 256) {
                int j = i / D, k = i % D;
                WSs[k * SW1 + j] = f2bf(s[i]);
            }
        }
        __syncthreads();
        // GEMM1: HB = relu(A1 @ W1c^T + b1c)   (256 thr, 4x4 tiles)
        {
            const int r0 = (tid >> 5) * 4;
            const int j0 = (tid & 31) * 4;
            float acc[4][4] = {};
            for (int k = 0; k < D; ++k) {
                float hr[4];
                #pragma unroll
                for (int i = 0; i < 4; ++i) hr[i] = A1[(r0 + i) * D + k];
                u32 wa = *(const u32*)&WSs[k * SW1 + j0];
                u32 wb = *(const u32*)&WSs[k * SW1 + j0 + 2];
                float wr[4] = { bflo(wa), bfhi(wa), bflo(wb), bfhi(wb) };
                #pragma unroll
                for (int i = 0; i < 4; ++i)
                    #pragma unroll
                    for (int j = 0; j < 4; ++j)
                        acc[i][j] += hr[i] * wr[j];
            }
            #pragma unroll
            for (int i = 0; i < 4; ++i) {
                float v0 = fmaxf(acc[i][0] + b1[ch * CH + j0 + 0], 0.f);
                float v1 = fmaxf(acc[i][1] + b1[ch * CH + j0 + 1], 0.f);
                float v2 = fmaxf(acc[i][2] + b1[ch * CH + j0 + 2], 0.f);
                float v3 = fmaxf(acc[i][3] + b1[ch * CH + j0 + 3], 0.f);
                HBu[(r0 + i) * 66 + (j0 >> 1)]     = ((u32)f2bf(v1) << 16) | f2bf(v0);
                HBu[(r0 + i) * 66 + (j0 >> 1) + 1] = ((u32)f2bf(v3) << 16) | f2bf(v2);
            }
        }
        __syncthreads();
        // stage W2 chunk transposed: WSs[jp*SW + c] = w2[c][ch*128 + jp]
        {
            for (int i = tid; i < D * CH; i += 256) {
                int c = i >> 7, jp = i & 127;
                WSs[jp * SW + c] = f2bf(w2[(size_t)c * FF + ch * CH + jp]);
            }
        }
        __syncthreads();
        // GEMM2: facc += HB @ W2c^T   (200 thr, 4x4 tiles, regs persist)
        if (tid < 200) {
            for (int j = 0; j < CH; j += 2) {
                u32 hp0 = HBu[(fr0 + 0) * 66 + (j >> 1)];
                u32 hp1 = HBu[(fr0 + 1) * 66 + (j >> 1)];
                u32 hp2 = HBu[(fr0 + 2) * 66 + (j >> 1)];
                u32 hp3 = HBu[(fr0 + 3) * 66 + (j >> 1)];
                u32 wa0 = *(const u32*)&WSs[j * SW + fc0];
                u32 wb0 = *(const u32*)&WSs[j * SW + fc0 + 2];
                u32 wa1 = *(const u32*)&WSs[(j + 1) * SW + fc0];
                u32 wb1 = *(const u32*)&WSs[(j + 1) * SW + fc0 + 2];
                float w00 = bflo(wa0), w01 = bfhi(wa0), w02 = bflo(wb0), w03 = bfhi(wb0);
                float w10 = bflo(wa1), w11 = bfhi(wa1), w12 = bflo(wb1), w13 = bfhi(wb1);
                float h0[4] = { bflo(hp0), bflo(hp1), bflo(hp2), bflo(hp3) };
                float h1[4] = { bfhi(hp0), bfhi(hp1), bfhi(hp2), bfhi(hp3) };
                #pragma unroll
                for (int i = 0; i < 4; ++i) {
                    facc[i][0] += h0[i] * w00; facc[i][1] += h0[i] * w01;
                    facc[i][2] += h0[i] * w02; facc[i][3] += h0[i] * w03;
                    facc[i][0] += h1[i] * w10; facc[i][1] += h1[i] * w11;
                    facc[i][2] += h1[i] * w12; facc[i][3] += h1[i] * w13;
                }
            }
        }
        __syncthreads();
    }

    // A0 = h + f2 + b2  (residual input to LN2)
    if (tid < 200) {
        #pragma unroll
        for (int i = 0; i < 4; ++i)
            #pragma unroll
            for (int j = 0; j < 4; ++j)
                A0[(fr0 + i) * D + fc0 + j] =
                    A1[(fr0 + i) * D + fc0 + j] + facc[i][j] + b2[fc0 + j];
    }
    __syncthreads();

    // s = LN2(h + f2) -> A0 (in place)
    layernorm_tile(A0, A0, ln2g, ln2b, tid);
    __syncthreads();

    // stage rec_emb [100][100] fp32 -> bf16 in LDS
    for (int i = tid; i < KP * D; i += 256)
        WSs[i] = f2bf(rec_emb[i]);
    __syncthreads();

    // out[b,k] = rec_b[idx] + dot(rec_emb[idx], s[b])
    for (int o = tid; o < ROWS * KP; o += 256) {
        int r = o / KP, k = o % KP;
        int grow = row0 + r;
        int idx  = ipred[(size_t)grow * KP + k];
        float s  = rec_b[idx];
        const float* sr = &A0[r * D];
        const u16*   rr = &WSs[idx * D];
        for (int d = 0; d < D; d += 2) {
            u32 rv = *(const u32*)&rr[d];
            s += sr[d] * bflo(rv) + sr[d + 1] * bfhi(rv);
        }
        out[(size_t)grow * KP + k] = s;
    }
}

extern "C" void kernel_launch(void* const* d_in, const int* in_sizes, int n_in,
                              void* d_out, int out_size, void* d_ws, size_t ws_size,
                              hipStream_t stream)
{
    const int*   item_seq   = (const int*)d_in[0];
    const int*   ipred      = (const int*)d_in[1];
    const float* item_emb   = (const float*)d_in[2];
    const float* rec_emb    = (const float*)d_in[3];
    const float* rec_b      = (const float*)d_in[4];
    const float* in_proj_w  = (const float*)d_in[5];
    const float* in_proj_b  = (const float*)d_in[6];
    const float* out_proj_w = (const float*)d_in[7];
    const float* out_proj_b = (const float*)d_in[8];
    const float* ln1g = (const float*)d_in[9];
    const float* ln1b = (const float*)d_in[10];
    const float* ln2g = (const float*)d_in[11];
    const float* ln2b = (const float*)d_in[12];
    const float* w1   = (const float*)d_in[13];
    const float* b1   = (const float*)d_in[14];
    const float* w2   = (const float*)d_in[15];
    const float* b2   = (const float*)d_in[16];
    float* xws = (float*)d_ws;

    k_gather<<<NB / 4, 256, 0, stream>>>(item_seq, item_emb, xws);
    k_fused<<<NB / ROWS, 256, 0, stream>>>(xws, ipred, rec_emb, rec_b,
        in_proj_w, in_proj_b, out_proj_w, out_proj_b,
        ln1g, ln1b, ln2g, ln2b, w1, b1, w2, b2, (float*)d_out);
}

// Round 4
// 681.938 us; speedup vs baseline: 1.3739x; 1.3739x over previous
//
#include <hip/hip_runtime.h>

#define NB   16384
#define LSEQ 50
#define D    100
#define KP   100
#define FF   2048
#define CH   128
#define NCH  (FF/CH)
#define ROWS 32
#define EPSV 1e-5f
#define SWB  136      // LDS u16 stride for MFMA tiles (68 dwords -> conflict-optimal)

typedef unsigned short u16;
typedef unsigned int   u32;
typedef __attribute__((ext_vector_type(8))) short bf16x8;
typedef __attribute__((ext_vector_type(4))) float f32x4;

// d_ws layout: [0, NB*D) fp32 xws ; then u16 region:
#define WVP_OFF  0
#define WOP_OFF  14336
#define W1P_OFF  28672      // [2048][128]
#define W2P_OFF  290816     // [112][2048]
#define REC_OFF  520192     // [100][100]
#define PREP_N   530192

__device__ __forceinline__ float bflo(u32 u){ return __uint_as_float(u << 16); }
__device__ __forceinline__ float bfhi(u32 u){ return __uint_as_float(u & 0xffff0000u); }
__device__ __forceinline__ u16 f2bf(float f){
    u32 b = __float_as_uint(f);
    b += 0x7fffu + ((b >> 16) & 1u);   // RNE
    return (u16)(b >> 16);
}

// ---------------- Kernel 0: weight prep -> padded bf16 layouts ---------------
__global__ __launch_bounds__(256) void k_prep(
    const float* __restrict__ ipw, const float* __restrict__ opw,
    const float* __restrict__ w1,  const float* __restrict__ w2,
    const float* __restrict__ rec, u16* __restrict__ dst)
{
    int i = blockIdx.x * 256 + threadIdx.x;
    if (i >= PREP_N) return;
    if (i < WOP_OFF) {                       // Wv padded [112][128]
        int n = i >> 7, k = i & 127;
        dst[i] = (n < D && k < D) ? f2bf(ipw[2*D*D + n*D + k]) : (u16)0;
    } else if (i < W1P_OFF) {                // Wo padded [112][128]
        int j = i - WOP_OFF; int n = j >> 7, k = j & 127;
        dst[i] = (n < D && k < D) ? f2bf(opw[n*D + k]) : (u16)0;
    } else if (i < W2P_OFF) {                // W1 padded [2048][128]
        int j = i - W1P_OFF; int n = j >> 7, k = j & 127;
        dst[i] = (k < D) ? f2bf(w1[n*D + k]) : (u16)0;
    } else if (i < REC_OFF) {                // W2 padded [112][2048]
        int j = i - W2P_OFF; int c = j >> 11, jj = j & 2047;
        dst[i] = (c < D) ? f2bf(w2[c*FF + jj]) : (u16)0;
    } else {                                 // rec_emb bf16 [100][100]
        int j = i - REC_OFF;
        dst[i] = f2bf(rec[j]);
    }
}

// ---------------- Kernel 1: x = sum_l item_emb[item_seq[b,l]]  (fp32) --------
__global__ __launch_bounds__(256) void k_gather(const int* __restrict__ seq,
        const float* __restrict__ emb, float* __restrict__ xout)
{
    __shared__ float2 part[5][50];
    const int row = blockIdx.x;
    const int t   = threadIdx.x;
    const int c2  = t % 50;          // float2 column
    const int lg  = t / 50;          // 0..5 (group 5 idle)
    float ax = 0.f, ay = 0.f;
    if (lg < 5) {
        const float2* e2 = (const float2*)emb;
        #pragma unroll
        for (int u = 0; u < 10; ++u) {
            int idx = seq[row * LSEQ + lg * 10 + u];
            float2 w = e2[(size_t)idx * 50 + c2];
            ax += w.x; ay += w.y;
        }
        float2 p; p.x = ax; p.y = ay;
        part[lg][c2] = p;
    }
    __syncthreads();
    if (t < 50) {
        float sx = 0.f, sy = 0.f;
        #pragma unroll
        for (int g = 0; g < 5; ++g) { sx += part[g][t].x; sy += part[g][t].y; }
        float2 v; v.x = sx; v.y = sy;
        ((float2*)xout)[(size_t)row * 50 + t] = v;
    }
}

// ---------------- Kernel 2: fused transformer block + scoring (MFMA) ---------
__device__ __forceinline__ void gemm2x2(
    const u16* __restrict__ Alds, const u16* __restrict__ Blds,
    int n0, int nvalid, int fl, int fq, f32x4 acc[2][2])
{
    #pragma unroll
    for (int ks = 0; ks < 4; ++ks) {
        const int kb = ks * 32 + fq * 8;
        bf16x8 a0 = *(const bf16x8*)(Alds + fl * SWB + kb);
        bf16x8 a1 = *(const bf16x8*)(Alds + (16 + fl) * SWB + kb);
        bf16x8 b0 = *(const bf16x8*)(Blds + (n0 + fl) * SWB + kb);
        acc[0][0] = __builtin_amdgcn_mfma_f32_16x16x32_bf16(a0, b0, acc[0][0], 0, 0, 0);
        acc[1][0] = __builtin_amdgcn_mfma_f32_16x16x32_bf16(a1, b0, acc[1][0], 0, 0, 0);
        if (nvalid > 1) {
            bf16x8 b1 = *(const bf16x8*)(Blds + (n0 + 16 + fl) * SWB + kb);
            acc[0][1] = __builtin_amdgcn_mfma_f32_16x16x32_bf16(a0, b1, acc[0][1], 0, 0, 0);
            acc[1][1] = __builtin_amdgcn_mfma_f32_16x16x32_bf16(a1, b1, acc[1][1], 0, 0, 0);
        }
    }
}

template<bool TOBF>
__device__ __forceinline__ void ln_tile(float* __restrict__ A, u16* __restrict__ dstbf,
        const float* __restrict__ g, const float* __restrict__ b, int tid)
{
    const int r  = tid >> 3;
    const int s8 = tid & 7;
    float sum = 0.f, sq = 0.f;
    for (int k = s8; k < D; k += 8) {
        float v = A[r * 104 + k];
        sum += v; sq += v * v;
    }
    sum += __shfl_xor(sum, 1, 64); sq += __shfl_xor(sq, 1, 64);
    sum += __shfl_xor(sum, 2, 64); sq += __shfl_xor(sq, 2, 64);
    sum += __shfl_xor(sum, 4, 64); sq += __shfl_xor(sq, 4, 64);
    float m   = sum * 0.01f;
    float var = sq * 0.01f - m * m;
    float rs  = rsqrtf(var + EPSV);
    for (int k = s8; k < D; k += 8) {
        float v = A[r * 104 + k];
        float y = (v - m) * rs * g[k] + b[k];
        A[r * 104 + k] = y;
        if (TOBF) dstbf[r * SWB + k] = f2bf(y);
    }
}

__global__ __launch_bounds__(256) void k_fused(
    const float* __restrict__ xin,
    const int*  __restrict__ ipred,
    const u16*  __restrict__ wbase,        // prep region
    const float* __restrict__ rec_b,
    const float* __restrict__ in_proj_b, const float* __restrict__ out_proj_b,
    const float* __restrict__ ln1g, const float* __restrict__ ln1b,
    const float* __restrict__ ln2g, const float* __restrict__ ln2b,
    const float* __restrict__ b1, const float* __restrict__ b2,
    float* __restrict__ out)
{
    __shared__ __align__(16) float A0[ROWS * 104];     // x -> x+attn -> h -> h+f2 -> s
    __shared__ __align__(16) u16   Abf[ROWS * SWB];    // x -> v -> h (bf16, A-operand)
    __shared__ __align__(16) u16   Hbf[ROWS * SWB];    // H chunk (bf16, A-operand)
    __shared__ __align__(16) u16   Wbuf[128 * SWB];    // B-operand weight tile / rec

    const int tid  = threadIdx.x;
    const int wv   = tid >> 6;
    const int lane = tid & 63;
    const int fl   = lane & 15;
    const int fq   = lane >> 4;
    const int row0 = blockIdx.x * ROWS;
    const int n0   = wv * 32;
    const int nv7  = (wv < 3) ? 2 : 1;    // 7 N-tiles over 4 waves

    const u16* Wvp = wbase + WVP_OFF;
    const u16* Wop = wbase + WOP_OFF;
    const u16* W1p = wbase + W1P_OFF;
    const u16* W2p = wbase + W2P_OFF;
    const u16* recp= wbase + REC_OFF;

    // stage x (fp32 + bf16 padded) and Wv tile
    for (int i = tid; i < ROWS * 128; i += 256) {
        int r = i >> 7, k = i & 127;
        float v = (k < D) ? xin[(size_t)(row0 + r) * D + k] : 0.f;
        if (k < D) A0[r * 104 + k] = v;
        Abf[r * SWB + k] = f2bf(v);
    }
    for (int i = tid; i < 112 * 16; i += 256) {
        int r = i >> 4, cb = (i & 15) * 8;
        *(uint4*)(Wbuf + r * SWB + cb) = *(const uint4*)(Wvp + r * 128 + cb);
    }
    __syncthreads();

    // ---- GEMM V: v = x @ Wv^T + bv ----
    {
        f32x4 acc[2][2] = {};
        gemm2x2(Abf, Wbuf, n0, nv7, fl, fq, acc);
        __syncthreads();                       // all reads of Abf(x)/Wbuf(Wv) done
        for (int t = 0; t < nv7; ++t) {
            int c = n0 + t * 16 + fl;
            if (c < D) {
                float bvc = in_proj_b[2 * D + c];
                #pragma unroll
                for (int r = 0; r < 4; ++r) {
                    int m = fq * 4 + r;
                    Abf[m * SWB + c]        = f2bf(acc[0][t][r] + bvc);
                    Abf[(16 + m) * SWB + c] = f2bf(acc[1][t][r] + bvc);
                }
            }
        }
        for (int i = tid; i < 112 * 16; i += 256) {
            int r = i >> 4, cb = (i & 15) * 8;
            *(uint4*)(Wbuf + r * SWB + cb) = *(const uint4*)(Wop + r * 128 + cb);
        }
        __syncthreads();
    }

    // ---- GEMM O: attn = v @ Wo^T + bo ; A0 += attn ----
    {
        f32x4 acc[2][2] = {};
        gemm2x2(Abf, Wbuf, n0, nv7, fl, fq, acc);
        for (int t = 0; t < nv7; ++t) {
            int c = n0 + t * 16 + fl;
            if (c < D) {
                float boc = out_proj_b[c];
                #pragma unroll
                for (int r = 0; r < 4; ++r) {
                    int m = fq * 4 + r;
                    A0[m * 104 + c]        += acc[0][t][r] + boc;
                    A0[(16 + m) * 104 + c] += acc[1][t][r] + boc;
                }
            }
        }
        __syncthreads();
    }

    // ---- LN1: h = LN(x+attn) -> A0 (fp32) + Abf (bf16) ----
    ln_tile<true>(A0, Abf, ln1g, ln1b, tid);

    // ---- FFN: 16 chunks of 128 hidden ----
    f32x4 facc[2][2] = {};
    for (int ch = 0; ch < NCH; ++ch) {
        __syncthreads();           // prev gemm2 reads done (also LN1 writes visible)
        {
            const u16* src = W1p + (size_t)ch * CH * 128;
            for (int i = tid; i < 128 * 16; i += 256) {
                int r = i >> 4, cb = (i & 15) * 8;
                *(uint4*)(Wbuf + r * SWB + cb) = *(const uint4*)(src + r * 128 + cb);
            }
        }
        __syncthreads();
        // GEMM1: H = relu(h @ W1c^T + b1c)
        f32x4 hacc[2][2] = {};
        gemm2x2(Abf, Wbuf, n0, 2, fl, fq, hacc);
        __syncthreads();           // gemm1 reads done; Wbuf/Hbf free to overwrite
        #pragma unroll
        for (int t = 0; t < 2; ++t) {
            int c = n0 + t * 16 + fl;
            float b1c = b1[ch * CH + c];
            #pragma unroll
            for (int r = 0; r < 4; ++r) {
                int m = fq * 4 + r;
                Hbf[m * SWB + c]        = f2bf(fmaxf(hacc[0][t][r] + b1c, 0.f));
                Hbf[(16 + m) * SWB + c] = f2bf(fmaxf(hacc[1][t][r] + b1c, 0.f));
            }
        }
        {
            const u16* src = W2p + ch * CH;
            for (int i = tid; i < 112 * 16; i += 256) {
                int r = i >> 4, cb = (i & 15) * 8;
                *(uint4*)(Wbuf + r * SWB + cb) = *(const uint4*)(src + (size_t)r * FF + cb);
            }
        }
        __syncthreads();
        // GEMM2: facc += H @ W2c^T
        gemm2x2(Hbf, Wbuf, n0, nv7, fl, fq, facc);
    }

    // ---- A0 = h + f2 + b2 ----
    for (int t = 0; t < nv7; ++t) {
        int c = n0 + t * 16 + fl;
        if (c < D) {
            float b2c = b2[c];
            #pragma unroll
            for (int r = 0; r < 4; ++r) {
                int m = fq * 4 + r;
                A0[m * 104 + c]        += facc[0][t][r] + b2c;
                A0[(16 + m) * 104 + c] += facc[1][t][r] + b2c;
            }
        }
    }
    __syncthreads();

    // ---- LN2 -> s (fp32 in A0); stage rec_emb bf16 into Wbuf ----
    ln_tile<false>(A0, nullptr, ln2g, ln2b, tid);
    for (int i = tid; i < 1250; i += 256)          // 1250 uint4 = 10000 u16 (FIX)
        *(uint4*)(Wbuf + i * 8) = *(const uint4*)(recp + i * 8);
    __syncthreads();

    // ---- scoring: out[b,k] = rec_b[idx] + dot(rec_emb[idx], s[b]) ----
    for (int o = tid; o < ROWS * KP; o += 256) {
        int r = o / KP, k = o % KP;
        int grow = row0 + r;
        int idx  = ipred[(size_t)grow * KP + k];
        float s  = rec_b[idx];
        const float* sr = &A0[r * 104];
        const u16*   rr = Wbuf + idx * D;
        for (int d = 0; d < D; d += 2) {
            u32 rv = *(const u32*)(rr + d);
            s += sr[d] * bflo(rv) + sr[d + 1] * bfhi(rv);
        }
        out[(size_t)grow * KP + k] = s;
    }
}

extern "C" void kernel_launch(void* const* d_in, const int* in_sizes, int n_in,
                              void* d_out, int out_size, void* d_ws, size_t ws_size,
                              hipStream_t stream)
{
    const int*   item_seq   = (const int*)d_in[0];
    const int*   ipred      = (const int*)d_in[1];
    const float* item_emb   = (const float*)d_in[2];
    const float* rec_emb    = (const float*)d_in[3];
    const float* rec_b      = (const float*)d_in[4];
    const float* in_proj_w  = (const float*)d_in[5];
    const float* in_proj_b  = (const float*)d_in[6];
    const float* out_proj_w = (const float*)d_in[7];
    const float* out_proj_b = (const float*)d_in[8];
    const float* ln1g = (const float*)d_in[9];
    const float* ln1b = (const float*)d_in[10];
    const float* ln2g = (const float*)d_in[11];
    const float* ln2b = (const float*)d_in[12];
    const float* w1   = (const float*)d_in[13];
    const float* b1   = (const float*)d_in[14];
    const float* w2   = (const float*)d_in[15];
    const float* b2   = (const float*)d_in[16];

    float* xws   = (float*)d_ws;
    u16*   wbase = (u16*)((float*)d_ws + (size_t)NB * D);

    k_prep<<<(PREP_N + 255) / 256, 256, 0, stream>>>(
        in_proj_w, out_proj_w, w1, w2, rec_emb, wbase);
    k_gather<<<NB, 256, 0, stream>>>(item_seq, item_emb, xws);
    k_fused<<<NB / ROWS, 256, 0, stream>>>(xws, ipred, wbase, rec_b,
        in_proj_b, out_proj_b, ln1g, ln1b, ln2g, ln2b, b1, b2, (float*)d_out);
}